// Round 2
// baseline (2918.286 us; speedup 1.0000x reference)
//
#include <hip/hip_runtime.h>
#include <hip/hip_bf16.h>

// BRC layer: 3 batched GEMMs (x @ U^T) + elementwise-independent bistable scan.
// Round 2: fp32-quality GEMM via split-fp16 (Markidis): x=xhi+xlo, U=Uhi+Ulo,
//   C = Ah*Bh + Ah*Bl + Al*Bh accumulated in fp32 MFMA (lo*lo dropped ~2^-24).
//   Needed because the bistable recurrence amplifies pre-activation error ~1e3x
//   over 2048 steps; plain fp16 (2.4e-4 rel) flipped attractors (absmax 1.89).
// Chunk buffer layout (m, j, {c,a,h}) so scan does one 12B load per step.
// ws: [xhi 16.8MB][xlo 16.8MB][Uhi .75MB][Ulo .75MB][chunk 201MB][h 256KB] ~236MB

typedef _Float16 half8 __attribute__((ext_vector_type(8)));
typedef float    f32x4 __attribute__((ext_vector_type(4)));

#define SEQ   2048
#define BATCH 128
#define INP   256
#define HID   512
#define CHUNK_T 256
#define NCHUNK  8
#define MLOC  (CHUNK_T * BATCH)        // 32768 rows per chunk
#define BJ    (BATCH * HID)            // 65536 recurrence strands

// ---------------- fp32 -> (fp16 hi, fp16 lo) split, 8 elems/thread/iter -----
__global__ __launch_bounds__(256) void cvt_split(
    const float* __restrict__ src, _Float16* __restrict__ hi,
    _Float16* __restrict__ lo, int n8)
{
    int i = blockIdx.x * blockDim.x + threadIdx.x;
    int stride = gridDim.x * blockDim.x;
    for (; i < n8; i += stride) {
        f32x4 a = ((const f32x4*)src)[2 * i];
        f32x4 b = ((const f32x4*)src)[2 * i + 1];
        half8 h, l;
#pragma unroll
        for (int k = 0; k < 4; ++k) {
            _Float16 hh = (_Float16)a[k];
            h[k] = hh; l[k] = (_Float16)(a[k] - (float)hh);
        }
#pragma unroll
        for (int k = 0; k < 4; ++k) {
            _Float16 hh = (_Float16)b[k];
            h[4 + k] = hh; l[4 + k] = (_Float16)(b[k] - (float)hh);
        }
        ((half8*)hi)[i] = h;
        ((half8*)lo)[i] = l;
    }
}

// ---------------- async 16B global->LDS ----------------
__device__ __forceinline__ void llds16(const void* g, void* l)
{
    __builtin_amdgcn_global_load_lds(
        (const __attribute__((address_space(1))) unsigned int*)g,
        (__attribute__((address_space(3))) unsigned int*)l,
        16, 0, 0);
}

// ---------------- GEMM: C[m, g, j] = sum_k A[m,k] * B[g*512+j, k] -----------
// A planes: (MLOC x 256) fp16.  B planes: (1536 x 256) fp16 = U_c|U_a|U_h rows.
// C: interleaved (MLOC x 512 x 3) fp32: addr = m*1536 + j*3 + g.
// Block: 256 thr = 4 waves; tile 128(M) x 128(N); K=256 in 4 steps of 64.
// LDS slot(r,cg) = r*8 + (cg ^ (r&7)); swizzle applied on the GLOBAL side so
// global_load_lds (wave-uniform base + lane*16) lands each lane correctly.
__global__ __launch_bounds__(256) void gemm_xu(
    const _Float16* __restrict__ Ah, const _Float16* __restrict__ Al,
    const _Float16* __restrict__ Bh, const _Float16* __restrict__ Bl,
    float* __restrict__ C)
{
    __shared__ __align__(16) _Float16 AsH[8192];  // 16 KB each
    __shared__ __align__(16) _Float16 AsL[8192];
    __shared__ __align__(16) _Float16 BsH[8192];
    __shared__ __align__(16) _Float16 BsL[8192];

    const int tid  = threadIdx.x;
    const int lane = tid & 63;
    const int wv   = tid >> 6;       // wave 0..3
    const int quad = lane >> 4;      // 0..3
    const int l16  = lane & 15;
    const int m0   = blockIdx.x * 128;   // row tile within chunk
    const int n0   = blockIdx.y * 128;   // col tile within 1536
    const int wm   = (wv >> 1) * 64;     // wave quadrant
    const int wn   = (wv & 1) * 64;

    f32x4 acc[4][4];
    const f32x4 zero = {0.0f, 0.0f, 0.0f, 0.0f};
#pragma unroll
    for (int i = 0; i < 4; ++i)
#pragma unroll
        for (int j = 0; j < 4; ++j) acc[i][j] = zero;

    for (int ko = 0; ko < 4; ++ko) {
        const int k0 = ko * 64;
        __syncthreads();
#pragma unroll
        for (int i = 0; i < 4; ++i) {
            const int s  = i * 256 + tid;
            const int r  = s >> 3;
            const int cg = (s & 7) ^ (r & 7);
            const size_t ga = (size_t)(m0 + r) * INP + k0 + cg * 8;
            const size_t gb = (size_t)(n0 + r) * INP + k0 + cg * 8;
            const size_t dst = (size_t)(i * 256 + wv * 64) * 16;
            llds16(Ah + ga, (char*)AsH + dst);
            llds16(Al + ga, (char*)AsL + dst);
            llds16(Bh + gb, (char*)BsH + dst);
            llds16(Bl + gb, (char*)BsL + dst);
        }
        __syncthreads();
#pragma unroll
        for (int ks = 0; ks < 2; ++ks) {
            const int cgk = ks * 4 + quad;   // 16B group index within 8
            half8 ah[4], al[4], bh[4], bl[4];
#pragma unroll
            for (int mf = 0; mf < 4; ++mf) {
                const int row = wm + mf * 16 + l16;
                const size_t off = (size_t)(row * 8 + (cgk ^ (row & 7))) * 8;
                ah[mf] = *(const half8*)(AsH + off);
                al[mf] = *(const half8*)(AsL + off);
            }
#pragma unroll
            for (int nf = 0; nf < 4; ++nf) {
                const int row = wn + nf * 16 + l16;
                const size_t off = (size_t)(row * 8 + (cgk ^ (row & 7))) * 8;
                bh[nf] = *(const half8*)(BsH + off);
                bl[nf] = *(const half8*)(BsL + off);
            }
#pragma unroll
            for (int mf = 0; mf < 4; ++mf)
#pragma unroll
                for (int nf = 0; nf < 4; ++nf) {
                    acc[mf][nf] = __builtin_amdgcn_mfma_f32_16x16x32_f16(
                        ah[mf], bh[nf], acc[mf][nf], 0, 0, 0);
                    acc[mf][nf] = __builtin_amdgcn_mfma_f32_16x16x32_f16(
                        ah[mf], bl[nf], acc[mf][nf], 0, 0, 0);
                    acc[mf][nf] = __builtin_amdgcn_mfma_f32_16x16x32_f16(
                        al[mf], bh[nf], acc[mf][nf], 0, 0, 0);
                }
        }
    }

    // epilogue: D frag layout col=lane&15, row=quad*4+reg (m89/m91 verified)
    const int g   = n0 >> 9;        // which matrix (c/a/h)
    const int nIn = n0 & 511;       // col base within matrix
#pragma unroll
    for (int mf = 0; mf < 4; ++mf)
#pragma unroll
        for (int nf = 0; nf < 4; ++nf)
#pragma unroll
            for (int r = 0; r < 4; ++r) {
                const int m = m0 + wm + mf * 16 + quad * 4 + r;
                const int j = nIn + wn + nf * 16 + l16;
                C[(size_t)m * 1536 + (size_t)j * 3 + g] = acc[mf][nf][r];
            }
}

// ---------------- recurrence scan: one thread per (b, j) ----------------
__device__ __forceinline__ float tanh_acc(float z)
{
    // 1 - 2/(exp(2z)+1): exact saturation at +/-inf, ~1e-7 abs error
    return 1.0f - 2.0f / (expf(2.0f * z) + 1.0f);
}

__global__ __launch_bounds__(256) void brc_scan(
    const float* __restrict__ X,      // (MLOC, 512, 3) interleaved xc,xa,xh
    const float* __restrict__ h_in, float* __restrict__ h_out,
    const float* __restrict__ wc, const float* __restrict__ bc,
    const float* __restrict__ wa, const float* __restrict__ ba,
    float* __restrict__ out)
{
    const int bj = blockIdx.x * 256 + threadIdx.x;   // 0..65535
    const int j  = bj & (HID - 1);
    float h = h_in[bj];
    const float wcj = wc[j], bcj = bc[j];
    const float waj = wa[j], baj = ba[j];

    size_t idx = (size_t)bj * 3;
    float nxc = X[idx], nxa = X[idx + 1], nxh = X[idx + 2];
    const size_t step = (size_t)BJ * 3;

    for (int t = 0; t < CHUNK_T; ++t) {
        const float xc = nxc, xa = nxa, xh = nxh;
        idx += step;
        if (t + 1 < CHUNK_T) {         // prefetch next step (uniform branch)
            nxc = X[idx]; nxa = X[idx + 1]; nxh = X[idx + 2];
        }
        const float c  = 1.0f / (1.0f + expf(-(xc + bcj + wcj * h)));
        const float a  = 1.0f + tanh_acc(xa + baj + waj * h);
        const float th = tanh_acc(xh + a * h);
        h = c * h + (1.0f - c) * th;
        out[(size_t)t * BJ + bj] = h;
    }
    h_out[bj] = h;
}

// ---------------- launch ----------------
extern "C" void kernel_launch(void* const* d_in, const int* in_sizes, int n_in,
                              void* d_out, int out_size, void* d_ws, size_t ws_size,
                              hipStream_t stream)
{
    const float* x  = (const float*)d_in[0];
    const float* h0 = (const float*)d_in[1];
    const float* Uc = (const float*)d_in[2];
    const float* wc = (const float*)d_in[3];
    const float* bc = (const float*)d_in[4];
    const float* Ua = (const float*)d_in[5];
    const float* wa = (const float*)d_in[6];
    const float* ba = (const float*)d_in[7];
    const float* Uh = (const float*)d_in[8];
    float* out = (float*)d_out;

    char* ws = (char*)d_ws;
    const size_t XCH = (size_t)MLOC * INP;            // 8388608 halves/plane
    _Float16* xhi = (_Float16*)ws;                    // 16.8 MB
    _Float16* xlo = xhi + XCH;                        // 16.8 MB
    _Float16* Uhi = xlo + XCH;                        // 1536*256 halves
    _Float16* Ulo = Uhi + (size_t)3 * HID * INP;
    float* chunkBuf = (float*)(Ulo + (size_t)3 * HID * INP);  // MLOC*1536 f32
    float* hstate = chunkBuf + (size_t)MLOC * 1536;   // 65536 f32

    // U splits (tiny, once)
    cvt_split<<<64, 256, 0, stream>>>(Uc, Uhi,                 Ulo,                 HID * INP / 8);
    cvt_split<<<64, 256, 0, stream>>>(Ua, Uhi + HID * INP,     Ulo + HID * INP,     HID * INP / 8);
    cvt_split<<<64, 256, 0, stream>>>(Uh, Uhi + 2 * HID * INP, Ulo + 2 * HID * INP, HID * INP / 8);

    for (int chunk = 0; chunk < NCHUNK; ++chunk) {
        const float* xc = x + (size_t)chunk * MLOC * INP;
        cvt_split<<<4096, 256, 0, stream>>>(xc, xhi, xlo, MLOC * INP / 8);

        gemm_xu<<<dim3(256, 12), 256, 0, stream>>>(xhi, xlo, Uhi, Ulo, chunkBuf);

        const float* hin = (chunk == 0) ? h0 : hstate;
        float* hout = (chunk == NCHUNK - 1) ? (out + (size_t)SEQ * BJ) : hstate;
        brc_scan<<<256, 256, 0, stream>>>(
            chunkBuf, hin, hout, wc, bc, wa, ba,
            out + (size_t)chunk * CHUNK_T * BJ);
    }
}